// Round 4
// baseline (864.860 us; speedup 1.0000x reference)
//
#include <hip/hip_runtime.h>
#include <math.h>

// Sinkhorn loss, n=m=8192, K=32, eps=1, L=10 iterations.
// Round 8: revert round-7 (zq/32-bit regression). Occupancy lever on
// sink_pass: 32 rows/wave (was 64), grid (n/128, NPS) = 2048 WGs,
// __launch_bounds__(256,6) -> 6 waves/SIMD (was 4) to cover exp/MFMA/load
// latency. Per-cell math and accumulation order bit-identical to round 6
// (same jt/u/c ordering; only wave->row ownership changes). Loss unchanged.
//   pass:  psum_out[slice*n+i] = sum_{j in slice} exp2(z_ij) * pb_j
//   loss:  sum_ij fma(z,-ln2,xsq+ysq) * exp2(z) * pa_i * pb_j
// MFMA layouts (m89/m120-verified): A elem j = A[m=lane&15][k=(lane>>4)*8+j];
// C/D: col=lane&15, row=(lane>>4)*4+reg.

#define KDIM 32
#define NPS 32                    // psum slices (pass grid.y)
#define NSL_LOSS 16               // loss grid.y
#define LOG2E 1.44269504088896340736f
#define LN2 0.69314718055994530942f

typedef short short8 __attribute__((ext_vector_type(8)));
typedef float f32x4 __attribute__((ext_vector_type(4)));

__device__ __forceinline__ unsigned short f2bf(float f) {
    unsigned int u = __float_as_uint(f);
    u += 0x7FFF + ((u >> 16) & 1);
    return (unsigned short)(u >> 16);
}
__device__ __forceinline__ float bf2f(unsigned short b) {
    return __uint_as_float(((unsigned int)b) << 16);
}

// 3-term split product: z = aH*bh + aH*bl + aL*bh  (hi/lo bf16 emulated fp32)
static __device__ __forceinline__ f32x4 mfma3(const short8 aHt, const short8 aLt,
                                              const short8 bhu, const short8 blu) {
    f32x4 z = {0.f, 0.f, 0.f, 0.f};
    __builtin_amdgcn_s_setprio(1);
    z = __builtin_amdgcn_mfma_f32_16x16x32_bf16(aHt, bhu, z, 0, 0, 0);
    z = __builtin_amdgcn_mfma_f32_16x16x32_bf16(aHt, blu, z, 0, 0, 0);
    z = __builtin_amdgcn_mfma_f32_16x16x32_bf16(aLt, bhu, z, 0, 0, 0);
    __builtin_amdgcn_s_setprio(0);
    return z;
}

// ------------------------------------------------------------ prep: hi/lo split
// x side is pre-scaled by 2*log2e; y side unscaled.
__global__ void prep_split(const float* __restrict__ x, const float* __restrict__ y,
                           int nelem,
                           unsigned short* __restrict__ xh, unsigned short* __restrict__ xl,
                           unsigned short* __restrict__ yh, unsigned short* __restrict__ yl) {
    int i4 = (blockIdx.x * 256 + threadIdx.x) * 4;
    if (i4 >= 2 * nelem) return;
    const float* src; unsigned short* dh; unsigned short* dl; int off; float sc;
    if (i4 < nelem) { src = x; dh = xh; dl = xl; off = i4; sc = 2.0f * LOG2E; }
    else            { src = y; dh = yh; dl = yl; off = i4 - nelem; sc = 1.0f; }
    float4 v = *(const float4*)(src + off);
    v.x *= sc; v.y *= sc; v.z *= sc; v.w *= sc;
    ushort4 h, l;
    h.x = f2bf(v.x); l.x = f2bf(v.x - bf2f(h.x));
    h.y = f2bf(v.y); l.y = f2bf(v.y - bf2f(h.y));
    h.z = f2bf(v.z); l.z = f2bf(v.z - bf2f(h.z));
    h.w = f2bf(v.w); l.w = f2bf(v.w - bf2f(h.w));
    *(ushort4*)(dh + off) = h;
    *(ushort4*)(dl + off) = l;
}

// ------------------------------------------------------------ prep: row sumsq
// xsq/ysq raw; pb0 = exp(-ysq) multiplicative init bias (g0 = 0).
__global__ void prep_sq(const float* __restrict__ x, const float* __restrict__ y,
                        int n, float* __restrict__ xsq, float* __restrict__ ysq,
                        float* __restrict__ pb0) {
    int i = blockIdx.x * blockDim.x + threadIdx.x;
    if (i >= 2 * n) return;
    const float* src = (i < n) ? x : y;
    int r = (i < n) ? i : i - n;
    const float4* p = (const float4*)(src + (size_t)r * KDIM);
    float s = 0.f;
#pragma unroll
    for (int q = 0; q < 8; ++q) {
        float4 v = p[q];
        s += v.x * v.x + v.y * v.y + v.z * v.z + v.w * v.w;
    }
    if (i < n) xsq[r] = s;
    else { ysq[r] = s; pb0[r] = __builtin_amdgcn_exp2f(-LOG2E * s); }
}

// ------------------------------------------------------------ pass
// Wave = 32 rows; WG = 4 waves = 128 rows. grid = (n/128, NPS); slice 256 cols.
// 6 waves/SIMD target (was 4): latency-hiding probe + win.
__global__ __launch_bounds__(256, 6) void sink_pass(
    const unsigned short* __restrict__ Ah, const unsigned short* __restrict__ Alo,
    const unsigned short* __restrict__ Bh, const unsigned short* __restrict__ Blo,
    const float* __restrict__ pb_direct,     // pass 0: exp-bias, else null
    const float* __restrict__ psum_in,       // NPS-slice psums of prev pass
    float* __restrict__ psum_out, int n, float inv_n) {
    __shared__ float pbl[256];
    __shared__ float red[4][32][17];

    const int tid = threadIdx.x;
    const int w = tid >> 6, lane = tid & 63;
    const int mrow = lane & 15, quad = lane >> 4, koff = quad * 8;
    const int i0 = (blockIdx.x * 4 + w) * 32;
    const int jbeg = blockIdx.y * (n / NPS);

    {   // prologue: multiplicative bias for this slice's 256 cols
        int c = jbeg + tid;
        float b;
        if (pb_direct) {
            b = pb_direct[c];
        } else {
            float s = 0.f;
#pragma unroll
            for (int k = 0; k < NPS; ++k) s += psum_in[(size_t)k * n + c];
            b = inv_n / s;
        }
        pbl[tid] = b;
    }

    short8 aH[2], aL[2];
#pragma unroll
    for (int t = 0; t < 2; ++t) {
        size_t rb = (size_t)(i0 + t * 16 + mrow) * KDIM + koff;
        aH[t] = *(const short8*)(Ah + rb);
        aL[t] = *(const short8*)(Alo + rb);
    }
    __syncthreads();

    float rs[8];
#pragma unroll
    for (int q = 0; q < 8; ++q) rs[q] = 0.f;

    auto ldB = [&](int jt, short8* bh, short8* bl, float* pb) {
        const int j0 = jbeg + jt * 32;
#pragma unroll
        for (int u = 0; u < 2; ++u) {
            size_t rb = (size_t)(j0 + u * 16 + mrow) * KDIM + koff;
            bh[u] = *(const short8*)(Bh + rb);
            bl[u] = *(const short8*)(Blo + rb);
            pb[u] = pbl[jt * 32 + u * 16 + mrow];
        }
    };
    auto eproc = [&](const f32x4 z, int t, float pbu) {
#pragma unroll
        for (int r = 0; r < 4; ++r)
            rs[t * 4 + r] = fmaf(__builtin_amdgcn_exp2f(z[r]), pbu, rs[t * 4 + r]);
    };
    // Software-pipelined tile schedule (stage i MFMA overlaps stage i-1 exp);
    // accumulation order per rs element identical to plain (t,u) loop.
    auto compute = [&](short8* bh, short8* bl, float* pb) {
        f32x4 za, zb;
        za = mfma3(aH[0], aL[0], bh[0], bl[0]);
        zb = mfma3(aH[0], aL[0], bh[1], bl[1]);
        eproc(za, 0, pb[0]);
        za = mfma3(aH[1], aL[1], bh[0], bl[0]);
        eproc(zb, 0, pb[1]);
        zb = mfma3(aH[1], aL[1], bh[1], bl[1]);
        eproc(za, 1, pb[0]);
        eproc(zb, 1, pb[1]);
    };

    const int JT = (n / NPS) / 32;   // 8
    short8 bh0[2], bl0[2], bh1[2], bl1[2];
    float pb0v[2], pb1v[2];
    ldB(0, bh0, bl0, pb0v);
    for (int jt = 0; jt < JT; jt += 2) {
        ldB(jt + 1, bh1, bl1, pb1v);
        compute(bh0, bl0, pb0v);
        if (jt + 2 < JT) ldB(jt + 2, bh0, bl0, pb0v);
        compute(bh1, bl1, pb1v);
    }

#pragma unroll
    for (int t = 0; t < 2; ++t)
#pragma unroll
        for (int r = 0; r < 4; ++r)
            red[w][t * 16 + quad * 4 + r][mrow] = rs[t * 4 + r];
    __syncthreads();
    if (tid < 128) {
        int w2 = tid >> 5, row = tid & 31;
        float s = 0.f;
#pragma unroll
        for (int c = 0; c < 16; ++c) s += red[w2][row][c];
        psum_out[(size_t)blockIdx.y * n + blockIdx.x * 128 + tid] = s;
    }
}

// ------------------------------------------------------------ loss
// Wave = 32 rows; WG = 128 rows. grid = (n/128, NSL_LOSS), slice 512 cols.
// (unchanged from round 6 — protects exact final-sum order)
__global__ __launch_bounds__(256, 4) void sink_loss(
    const unsigned short* __restrict__ Xh, const unsigned short* __restrict__ Xl,
    const unsigned short* __restrict__ Yh, const unsigned short* __restrict__ Yl,
    const float* __restrict__ apsum, const float* __restrict__ bpsum,
    const float* __restrict__ xsq, const float* __restrict__ ysq,
    float* __restrict__ partials, int n, float inv_n) {
    __shared__ float pbL[512];
    __shared__ float ysl[512];
    __shared__ float pal[128];
    __shared__ float xsl[128];
    __shared__ float red[256];

    const int tid = threadIdx.x;
    const int w = tid >> 6, lane = tid & 63;
    const int mrow = lane & 15, quad = lane >> 4, koff = quad * 8;
    const int i0 = (blockIdx.x * 4 + w) * 32;
    const int jbeg = blockIdx.y * (n / NSL_LOSS);   // 512 cols

#pragma unroll
    for (int h = 0; h < 2; ++h) {
        int c = tid + h * 256;
        int j = jbeg + c;
        float s = 0.f;
#pragma unroll
        for (int k = 0; k < NPS; ++k) s += bpsum[(size_t)k * n + j];
        pbL[c] = inv_n / s;
        ysl[c] = ysq[j];
    }
    if (tid < 128) {
        int i = blockIdx.x * 128 + tid;
        float s = 0.f;
#pragma unroll
        for (int k = 0; k < NPS; ++k) s += apsum[(size_t)k * n + i];
        pal[tid] = inv_n / s;
        xsl[tid] = xsq[i];
    }

    short8 aH[2], aL[2];
#pragma unroll
    for (int t = 0; t < 2; ++t) {
        size_t rb = (size_t)(i0 + t * 16 + mrow) * KDIM + koff;
        aH[t] = *(const short8*)(Xh + rb);
        aL[t] = *(const short8*)(Xl + rb);
    }
    __syncthreads();

    float pa[8], xs[8];
#pragma unroll
    for (int t = 0; t < 2; ++t)
#pragma unroll
        for (int r = 0; r < 4; ++r) {
            int rl = w * 32 + t * 16 + quad * 4 + r;
            pa[t * 4 + r] = pal[rl];
            xs[t * 4 + r] = xsl[rl];
        }

    float acc = 0.f;

    auto ldB = [&](int jt, short8* bh, short8* bl, float* pb, float* ysv) {
#pragma unroll
        for (int u = 0; u < 2; ++u) {
            int cl = jt * 32 + u * 16 + mrow;
            size_t rb = (size_t)(jbeg + cl) * KDIM + koff;
            bh[u] = *(const short8*)(Yh + rb);
            bl[u] = *(const short8*)(Yl + rb);
            pb[u] = pbL[cl];
            ysv[u] = ysl[cl];
        }
    };
    auto eprocL = [&](const f32x4 z, int t, float pbu, float ysu) {
#pragma unroll
        for (int r = 0; r < 4; ++r) {
            float dd = z[r];
            float e = __builtin_amdgcn_exp2f(dd) * (pa[t * 4 + r] * pbu);
            float cst = fmaf(dd, -LN2, xs[t * 4 + r] + ysu);
            acc = fmaf(cst, e, acc);
        }
    };
    // Pipelined schedule preserving the original (t0,u0),(t0,u1),(t1,u0),(t1,u1)
    // accumulation order of acc.
    auto compute = [&](short8* bh, short8* bl, float* pb, float* ysv) {
        f32x4 za, zb;
        za = mfma3(aH[0], aL[0], bh[0], bl[0]);
        zb = mfma3(aH[0], aL[0], bh[1], bl[1]);
        eprocL(za, 0, pb[0], ysv[0]);
        za = mfma3(aH[1], aL[1], bh[0], bl[0]);
        eprocL(zb, 0, pb[1], ysv[1]);
        zb = mfma3(aH[1], aL[1], bh[1], bl[1]);
        eprocL(za, 1, pb[0], ysv[0]);
        eprocL(zb, 1, pb[1], ysv[1]);
    };

    const int JT = (n / NSL_LOSS) / 32;   // 16
    short8 bh0[2], bl0[2], bh1[2], bl1[2];
    float pb0v[2], pb1v[2], ys0v[2], ys1v[2];
    ldB(0, bh0, bl0, pb0v, ys0v);
    for (int jt = 0; jt < JT; jt += 2) {
        ldB(jt + 1, bh1, bl1, pb1v, ys1v);
        compute(bh0, bl0, pb0v, ys0v);
        if (jt + 2 < JT) ldB(jt + 2, bh0, bl0, pb0v, ys0v);
        compute(bh1, bl1, pb1v, ys1v);
    }

    red[tid] = acc;
    __syncthreads();
#pragma unroll
    for (int s = 128; s > 0; s >>= 1) {
        if (tid < s) red[tid] += red[tid + s];
        __syncthreads();
    }
    if (tid == 0) partials[blockIdx.y * gridDim.x + blockIdx.x] = red[0];
}

// ------------------------------------------------------------ final reduce
__global__ void sink_reduce(const float* __restrict__ p, int nb,
                            float* __restrict__ out) {
    __shared__ float red[256];
    int tid = threadIdx.x;
    float v = 0.f;
    for (int i = tid; i < nb; i += 256) v += p[i];
    red[tid] = v;
    __syncthreads();
#pragma unroll
    for (int s = 128; s > 0; s >>= 1) {
        if (tid < s) red[tid] += red[tid + s];
        __syncthreads();
    }
    if (tid == 0) out[0] = red[0];
}

// ------------------------------------------------------------ launch
extern "C" void kernel_launch(void* const* d_in, const int* in_sizes, int n_in,
                              void* d_out, int out_size, void* d_ws, size_t ws_size,
                              hipStream_t stream) {
    const float* x = (const float*)d_in[0];
    const float* y = (const float*)d_in[1];
    const int n = in_sizes[0] / KDIM;                 // 8192
    const int nelem = n * KDIM;
    const float inv_n = 1.0f / (float)n;

    float* ws = (float*)d_ws;
    float* xsq   = ws;                                //  n
    float* ysq   = ws + n;                            //  n
    float* pb0   = ws + 2 * n;                        //  n
    float* apsum = ws + 3 * n;                        //  NPS*n
    float* bpsum = ws + (3 + NPS) * n;                //  NPS*n
    float* part  = ws + (3 + 2 * NPS) * n;            //  pad n
    unsigned short* us = (unsigned short*)(ws + (4 + 2 * NPS) * n);
    unsigned short* xh = us;
    unsigned short* xl = us + nelem;
    unsigned short* yh = us + 2 * nelem;
    unsigned short* yl = us + 3 * nelem;

    dim3 pgrid(n / 128, NPS);                         // (64, 32) = 2048 WGs
    dim3 lgrid(n / 128, NSL_LOSS);                    // (64, 16) = 1024 WGs

    prep_split<<<(2 * nelem / 4 + 255) / 256, 256, 0, stream>>>(x, y, nelem, xh, xl, yh, yl);
    prep_sq<<<(2 * n + 255) / 256, 256, 0, stream>>>(x, y, n, xsq, ysq, pb0);

    sink_pass<<<pgrid, 256, 0, stream>>>(xh, xl, yh, yl, pb0, nullptr, apsum, n, inv_n);
    sink_pass<<<pgrid, 256, 0, stream>>>(yh, yl, xh, xl, nullptr, apsum, bpsum, n, inv_n);
    for (int t = 1; t < 10; ++t) {
        sink_pass<<<pgrid, 256, 0, stream>>>(xh, xl, yh, yl, nullptr, bpsum, apsum, n, inv_n);
        sink_pass<<<pgrid, 256, 0, stream>>>(yh, yl, xh, xl, nullptr, apsum, bpsum, n, inv_n);
    }
    sink_loss<<<lgrid, 256, 0, stream>>>(xh, xl, yh, yl, apsum, bpsum, xsq, ysq, part, n, inv_n);
    sink_reduce<<<1, 256, 0, stream>>>(part, (n / 128) * NSL_LOSS, (float*)d_out);
}

// Round 5
// 543.046 us; speedup vs baseline: 1.5926x; 1.5926x over previous
//
#include <hip/hip_runtime.h>
#include <math.h>

// Sinkhorn loss, n=m=8192, K=32, eps=1, L=10 iterations.
// Round 9: round-6 geometry (64 rows/wave, WG 256x256, grid (32,32)) but the
// B prefetch double-buffer moves from VGPRs (32 regs) to LDS (8 KB), staged
// cooperatively with a T14 load-early/write-late split. XOR slot swizzle
// (slot = quad ^ ((col>>1)&3)) makes ds_read_b128 2-way (free, m136).
// Frees ~32 VGPRs -> __launch_bounds__(256,5): 5 waves/SIMD, no spill
// (round-8 lesson: (256,6) + reg-buffers = scratch catastrophe).
// Numerics bit-identical to round 6 (same bytes, same MFMA chain, same order).
//   pass:  psum_out[slice*n+i] = sum_{j in slice} exp2(z_ij) * pb_j
//   loss:  sum_ij fma(z,-ln2,xsq+ysq) * exp2(z) * pa_i * pb_j
// MFMA layouts (m89/m120-verified): A elem j = A[m=lane&15][k=(lane>>4)*8+j];
// C/D: col=lane&15, row=(lane>>4)*4+reg.

#define KDIM 32
#define NPS 32                    // psum slices (pass grid.y)
#define NSL_LOSS 16               // loss grid.y
#define LOG2E 1.44269504088896340736f
#define LN2 0.69314718055994530942f

typedef short short8 __attribute__((ext_vector_type(8)));
typedef float f32x4 __attribute__((ext_vector_type(4)));

__device__ __forceinline__ unsigned short f2bf(float f) {
    unsigned int u = __float_as_uint(f);
    u += 0x7FFF + ((u >> 16) & 1);
    return (unsigned short)(u >> 16);
}
__device__ __forceinline__ float bf2f(unsigned short b) {
    return __uint_as_float(((unsigned int)b) << 16);
}

// 3-term split product: z = aH*bh + aH*bl + aL*bh  (hi/lo bf16 emulated fp32)
static __device__ __forceinline__ f32x4 mfma3(const short8 aHt, const short8 aLt,
                                              const short8 bhu, const short8 blu) {
    f32x4 z = {0.f, 0.f, 0.f, 0.f};
    __builtin_amdgcn_s_setprio(1);
    z = __builtin_amdgcn_mfma_f32_16x16x32_bf16(aHt, bhu, z, 0, 0, 0);
    z = __builtin_amdgcn_mfma_f32_16x16x32_bf16(aHt, blu, z, 0, 0, 0);
    z = __builtin_amdgcn_mfma_f32_16x16x32_bf16(aLt, bhu, z, 0, 0, 0);
    __builtin_amdgcn_s_setprio(0);
    return z;
}

// ------------------------------------------------------------ prep: hi/lo split
// x side is pre-scaled by 2*log2e; y side unscaled.
__global__ void prep_split(const float* __restrict__ x, const float* __restrict__ y,
                           int nelem,
                           unsigned short* __restrict__ xh, unsigned short* __restrict__ xl,
                           unsigned short* __restrict__ yh, unsigned short* __restrict__ yl) {
    int i4 = (blockIdx.x * 256 + threadIdx.x) * 4;
    if (i4 >= 2 * nelem) return;
    const float* src; unsigned short* dh; unsigned short* dl; int off; float sc;
    if (i4 < nelem) { src = x; dh = xh; dl = xl; off = i4; sc = 2.0f * LOG2E; }
    else            { src = y; dh = yh; dl = yl; off = i4 - nelem; sc = 1.0f; }
    float4 v = *(const float4*)(src + off);
    v.x *= sc; v.y *= sc; v.z *= sc; v.w *= sc;
    ushort4 h, l;
    h.x = f2bf(v.x); l.x = f2bf(v.x - bf2f(h.x));
    h.y = f2bf(v.y); l.y = f2bf(v.y - bf2f(h.y));
    h.z = f2bf(v.z); l.z = f2bf(v.z - bf2f(h.z));
    h.w = f2bf(v.w); l.w = f2bf(v.w - bf2f(h.w));
    *(ushort4*)(dh + off) = h;
    *(ushort4*)(dl + off) = l;
}

// ------------------------------------------------------------ prep: row sumsq
// xsq/ysq raw; pb0 = exp(-ysq) multiplicative init bias (g0 = 0).
__global__ void prep_sq(const float* __restrict__ x, const float* __restrict__ y,
                        int n, float* __restrict__ xsq, float* __restrict__ ysq,
                        float* __restrict__ pb0) {
    int i = blockIdx.x * blockDim.x + threadIdx.x;
    if (i >= 2 * n) return;
    const float* src = (i < n) ? x : y;
    int r = (i < n) ? i : i - n;
    const float4* p = (const float4*)(src + (size_t)r * KDIM);
    float s = 0.f;
#pragma unroll
    for (int q = 0; q < 8; ++q) {
        float4 v = p[q];
        s += v.x * v.x + v.y * v.y + v.z * v.z + v.w * v.w;
    }
    if (i < n) xsq[r] = s;
    else { ysq[r] = s; pb0[r] = __builtin_amdgcn_exp2f(-LOG2E * s); }
}

// ------------------------------------------------------------ pass
// Wave = 64 rows; WG = 4 waves = 256 rows. grid = (n/256, NPS); slice 256 cols.
// B chunks (32 cols, hi+lo = 4 KB) double-buffered in LDS, XOR-slot-swizzled.
__global__ __launch_bounds__(256, 5) void sink_pass(
    const unsigned short* __restrict__ Ah, const unsigned short* __restrict__ Alo,
    const unsigned short* __restrict__ Bh, const unsigned short* __restrict__ Blo,
    const float* __restrict__ pb_direct,     // pass 0: exp-bias, else null
    const float* __restrict__ psum_in,       // NPS-slice psums of prev pass
    float* __restrict__ psum_out, int n, float inv_n) {
    __shared__ float pbl[256];
    __shared__ float red[4][64][17];
    __shared__ unsigned short Bs[2][2][32 * KDIM];   // [buf][hi/lo][col*32 + slot*8]

    const int tid = threadIdx.x;
    const int w = tid >> 6, lane = tid & 63;
    const int mrow = lane & 15, quad = lane >> 4, koff = quad * 8;
    const int i0 = (blockIdx.x * 4 + w) * 64;
    const int jbeg = blockIdx.y * (n / NPS);

    {   // prologue: multiplicative bias for this slice's 256 cols
        int c = jbeg + tid;
        float b;
        if (pb_direct) {
            b = pb_direct[c];
        } else {
            float s = 0.f;
#pragma unroll
            for (int k = 0; k < NPS; ++k) s += psum_in[(size_t)k * n + c];
            b = inv_n / s;
        }
        pbl[tid] = b;
    }

    short8 aH[4], aL[4];
#pragma unroll
    for (int t = 0; t < 4; ++t) {
        size_t rb = (size_t)(i0 + t * 16 + mrow) * KDIM + koff;
        aH[t] = *(const short8*)(Ah + rb);
        aL[t] = *(const short8*)(Alo + rb);
    }

    // Cooperative staging geometry: waves 0,1 -> hi region, waves 2,3 -> lo.
    // Each lane handles 16B: col = (w&1)*16 + (lane>>2), raw slot = lane&3.
    const int s_reg = w >> 1;                          // 0 = hi, 1 = lo
    const int s_col = (w & 1) * 16 + (lane >> 2);      // 0..31 within chunk
    const int s_slot = lane & 3;                       // global 16B slot
    const int s_swz = s_slot ^ ((s_col >> 1) & 3);     // LDS 16B slot (swizzled)
    const unsigned short* s_base = (s_reg == 0 ? Bh : Blo);
    unsigned short* s_dst = &Bs[0][0][0] + (size_t)0;  // buf offset added per call

    auto stage_src = [&](int jt) {
        return s_base + (size_t)(jbeg + jt * 32 + s_col) * KDIM + s_slot * 8;
    };
    auto stage_write = [&](int b, short8 v) {
        *(short8*)&Bs[b][s_reg][s_col * KDIM + s_swz * 8] = v;
    };

    {   // prologue stage of chunk 0 into buf 0
        short8 v0 = *(const short8*)stage_src(0);
        stage_write(0, v0);
    }
    __syncthreads();

    float rs[16];
#pragma unroll
    for (int q = 0; q < 16; ++q) rs[q] = 0.f;

    auto ldB = [&](int b, int jt, short8* bh, short8* bl, float* pb) {
#pragma unroll
        for (int u = 0; u < 2; ++u) {
            int cl = u * 16 + mrow;
            int sl = quad ^ ((cl >> 1) & 3);
            bh[u] = *(const short8*)&Bs[b][0][cl * KDIM + sl * 8];
            bl[u] = *(const short8*)&Bs[b][1][cl * KDIM + sl * 8];
            pb[u] = pbl[jt * 32 + cl];
        }
    };
    auto eproc = [&](const f32x4 z, int t, float pbu) {
#pragma unroll
        for (int r = 0; r < 4; ++r)
            rs[t * 4 + r] = fmaf(__builtin_amdgcn_exp2f(z[r]), pbu, rs[t * 4 + r]);
    };
    // Software-pipelined tile schedule (stage i MFMA overlaps stage i-1 exp);
    // accumulation order per rs element identical to plain (t,u) loop.
    auto compute = [&](short8* bh, short8* bl, float* pb) {
        f32x4 za, zb;
        za = mfma3(aH[0], aL[0], bh[0], bl[0]);
        zb = mfma3(aH[0], aL[0], bh[1], bl[1]);
        eproc(za, 0, pb[0]);
        za = mfma3(aH[1], aL[1], bh[0], bl[0]);
        eproc(zb, 0, pb[1]);
        zb = mfma3(aH[1], aL[1], bh[1], bl[1]);
        eproc(za, 1, pb[0]);
        za = mfma3(aH[2], aL[2], bh[0], bl[0]);
        eproc(zb, 1, pb[1]);
        zb = mfma3(aH[2], aL[2], bh[1], bl[1]);
        eproc(za, 2, pb[0]);
        za = mfma3(aH[3], aL[3], bh[0], bl[0]);
        eproc(zb, 2, pb[1]);
        zb = mfma3(aH[3], aL[3], bh[1], bl[1]);
        eproc(za, 3, pb[0]);
        eproc(zb, 3, pb[1]);
    };

    const int JT = (n / NPS) / 32;   // 8
    short8 bh[2], bl[2];
    float pbv[2];
    for (int jt = 0; jt < JT; ++jt) {
        const int b = jt & 1;
        short8 v;
        if (jt + 1 < JT) v = *(const short8*)stage_src(jt + 1);  // issue early
        ldB(b, jt, bh, bl, pbv);
        compute(bh, bl, pbv);                                    // hides load
        if (jt + 1 < JT) stage_write(b ^ 1, v);                  // write late
        __syncthreads();
    }

#pragma unroll
    for (int t = 0; t < 4; ++t)
#pragma unroll
        for (int r = 0; r < 4; ++r)
            red[w][t * 16 + quad * 4 + r][mrow] = rs[t * 4 + r];
    __syncthreads();
    {
        int w2 = tid >> 6, row = tid & 63;
        float s = 0.f;
#pragma unroll
        for (int c = 0; c < 16; ++c) s += red[w2][row][c];
        psum_out[(size_t)blockIdx.y * n + (blockIdx.x * 4 + w2) * 64 + row] = s;
    }
}

// ------------------------------------------------------------ loss
// Wave = 32 rows; WG = 128 rows. grid = (n/128, NSL_LOSS), slice 512 cols.
// (unchanged from round 6 — protects exact final-sum order)
__global__ __launch_bounds__(256, 4) void sink_loss(
    const unsigned short* __restrict__ Xh, const unsigned short* __restrict__ Xl,
    const unsigned short* __restrict__ Yh, const unsigned short* __restrict__ Yl,
    const float* __restrict__ apsum, const float* __restrict__ bpsum,
    const float* __restrict__ xsq, const float* __restrict__ ysq,
    float* __restrict__ partials, int n, float inv_n) {
    __shared__ float pbL[512];
    __shared__ float ysl[512];
    __shared__ float pal[128];
    __shared__ float xsl[128];
    __shared__ float red[256];

    const int tid = threadIdx.x;
    const int w = tid >> 6, lane = tid & 63;
    const int mrow = lane & 15, quad = lane >> 4, koff = quad * 8;
    const int i0 = (blockIdx.x * 4 + w) * 32;
    const int jbeg = blockIdx.y * (n / NSL_LOSS);   // 512 cols

#pragma unroll
    for (int h = 0; h < 2; ++h) {
        int c = tid + h * 256;
        int j = jbeg + c;
        float s = 0.f;
#pragma unroll
        for (int k = 0; k < NPS; ++k) s += bpsum[(size_t)k * n + j];
        pbL[c] = inv_n / s;
        ysl[c] = ysq[j];
    }
    if (tid < 128) {
        int i = blockIdx.x * 128 + tid;
        float s = 0.f;
#pragma unroll
        for (int k = 0; k < NPS; ++k) s += apsum[(size_t)k * n + i];
        pal[tid] = inv_n / s;
        xsl[tid] = xsq[i];
    }

    short8 aH[2], aL[2];
#pragma unroll
    for (int t = 0; t < 2; ++t) {
        size_t rb = (size_t)(i0 + t * 16 + mrow) * KDIM + koff;
        aH[t] = *(const short8*)(Xh + rb);
        aL[t] = *(const short8*)(Xl + rb);
    }
    __syncthreads();

    float pa[8], xs[8];
#pragma unroll
    for (int t = 0; t < 2; ++t)
#pragma unroll
        for (int r = 0; r < 4; ++r) {
            int rl = w * 32 + t * 16 + quad * 4 + r;
            pa[t * 4 + r] = pal[rl];
            xs[t * 4 + r] = xsl[rl];
        }

    float acc = 0.f;

    auto ldB = [&](int jt, short8* bh, short8* bl, float* pb, float* ysv) {
#pragma unroll
        for (int u = 0; u < 2; ++u) {
            int cl = jt * 32 + u * 16 + mrow;
            size_t rb = (size_t)(jbeg + cl) * KDIM + koff;
            bh[u] = *(const short8*)(Yh + rb);
            bl[u] = *(const short8*)(Yl + rb);
            pb[u] = pbL[cl];
            ysv[u] = ysl[cl];
        }
    };
    auto eprocL = [&](const f32x4 z, int t, float pbu, float ysu) {
#pragma unroll
        for (int r = 0; r < 4; ++r) {
            float dd = z[r];
            float e = __builtin_amdgcn_exp2f(dd) * (pa[t * 4 + r] * pbu);
            float cst = fmaf(dd, -LN2, xs[t * 4 + r] + ysu);
            acc = fmaf(cst, e, acc);
        }
    };
    // Pipelined schedule preserving the original (t0,u0),(t0,u1),(t1,u0),(t1,u1)
    // accumulation order of acc.
    auto compute = [&](short8* bh, short8* bl, float* pb, float* ysv) {
        f32x4 za, zb;
        za = mfma3(aH[0], aL[0], bh[0], bl[0]);
        zb = mfma3(aH[0], aL[0], bh[1], bl[1]);
        eprocL(za, 0, pb[0], ysv[0]);
        za = mfma3(aH[1], aL[1], bh[0], bl[0]);
        eprocL(zb, 0, pb[1], ysv[1]);
        zb = mfma3(aH[1], aL[1], bh[1], bl[1]);
        eprocL(za, 1, pb[0], ysv[0]);
        eprocL(zb, 1, pb[1], ysv[1]);
    };

    const int JT = (n / NSL_LOSS) / 32;   // 16
    short8 bh0[2], bl0[2], bh1[2], bl1[2];
    float pb0v[2], pb1v[2], ys0v[2], ys1v[2];
    ldB(0, bh0, bl0, pb0v, ys0v);
    for (int jt = 0; jt < JT; jt += 2) {
        ldB(jt + 1, bh1, bl1, pb1v, ys1v);
        compute(bh0, bl0, pb0v, ys0v);
        if (jt + 2 < JT) ldB(jt + 2, bh0, bl0, pb0v, ys0v);
        compute(bh1, bl1, pb1v, ys1v);
    }

    red[tid] = acc;
    __syncthreads();
#pragma unroll
    for (int s = 128; s > 0; s >>= 1) {
        if (tid < s) red[tid] += red[tid + s];
        __syncthreads();
    }
    if (tid == 0) partials[blockIdx.y * gridDim.x + blockIdx.x] = red[0];
}

// ------------------------------------------------------------ final reduce
__global__ void sink_reduce(const float* __restrict__ p, int nb,
                            float* __restrict__ out) {
    __shared__ float red[256];
    int tid = threadIdx.x;
    float v = 0.f;
    for (int i = tid; i < nb; i += 256) v += p[i];
    red[tid] = v;
    __syncthreads();
#pragma unroll
    for (int s = 128; s > 0; s >>= 1) {
        if (tid < s) red[tid] += red[tid + s];
        __syncthreads();
    }
    if (tid == 0) out[0] = red[0];
}

// ------------------------------------------------------------ launch
extern "C" void kernel_launch(void* const* d_in, const int* in_sizes, int n_in,
                              void* d_out, int out_size, void* d_ws, size_t ws_size,
                              hipStream_t stream) {
    const float* x = (const float*)d_in[0];
    const float* y = (const float*)d_in[1];
    const int n = in_sizes[0] / KDIM;                 // 8192
    const int nelem = n * KDIM;
    const float inv_n = 1.0f / (float)n;

    float* ws = (float*)d_ws;
    float* xsq   = ws;                                //  n
    float* ysq   = ws + n;                            //  n
    float* pb0   = ws + 2 * n;                        //  n
    float* apsum = ws + 3 * n;                        //  NPS*n
    float* bpsum = ws + (3 + NPS) * n;                //  NPS*n
    float* part  = ws + (3 + 2 * NPS) * n;            //  pad n
    unsigned short* us = (unsigned short*)(ws + (4 + 2 * NPS) * n);
    unsigned short* xh = us;
    unsigned short* xl = us + nelem;
    unsigned short* yh = us + 2 * nelem;
    unsigned short* yl = us + 3 * nelem;

    dim3 pgrid(n / 256, NPS);                         // (32, 32) = 1024 WGs
    dim3 lgrid(n / 128, NSL_LOSS);                    // (64, 16) = 1024 WGs

    prep_split<<<(2 * nelem / 4 + 255) / 256, 256, 0, stream>>>(x, y, nelem, xh, xl, yh, yl);
    prep_sq<<<(2 * n + 255) / 256, 256, 0, stream>>>(x, y, n, xsq, ysq, pb0);

    sink_pass<<<pgrid, 256, 0, stream>>>(xh, xl, yh, yl, pb0, nullptr, apsum, n, inv_n);
    sink_pass<<<pgrid, 256, 0, stream>>>(yh, yl, xh, xl, nullptr, apsum, bpsum, n, inv_n);
    for (int t = 1; t < 10; ++t) {
        sink_pass<<<pgrid, 256, 0, stream>>>(xh, xl, yh, yl, nullptr, bpsum, apsum, n, inv_n);
        sink_pass<<<pgrid, 256, 0, stream>>>(yh, yl, xh, xl, nullptr, apsum, bpsum, n, inv_n);
    }
    sink_loss<<<lgrid, 256, 0, stream>>>(xh, xl, yh, yl, apsum, bpsum, xsq, ysq, part, n, inv_n);
    sink_reduce<<<1, 256, 0, stream>>>(part, (n / 128) * NSL_LOSS, (float*)d_out);
}

// Round 6
// 509.727 us; speedup vs baseline: 1.6967x; 1.0654x over previous
//
#include <hip/hip_runtime.h>
#include <math.h>

// Sinkhorn loss, n=m=8192, K=32, eps=1, L=10 iterations.
// Round 10: round-8 structure (32 rows/wave, reg double-buffer, barrier-free
// inner loop, grid (n/128, NPS)) with the spill fixed: __launch_bounds__(256,5)
// -> VGPR cap 102 >= ~90 live set (round 8's (256,6) cap 85 forced scratch,
// VGPR_Count=40, WRITE_SIZE=47MB, 865us). 5 waves/SIMD vs round-6's 4.
// Per-cell math and accumulation order bit-identical to rounds 6/8.
//   pass:  psum_out[slice*n+i] = sum_{j in slice} exp2(z_ij) * pb_j
//   loss:  sum_ij fma(z,-ln2,xsq+ysq) * exp2(z) * pa_i * pb_j
// MFMA layouts (m89/m120-verified): A elem j = A[m=lane&15][k=(lane>>4)*8+j];
// C/D: col=lane&15, row=(lane>>4)*4+reg.

#define KDIM 32
#define NPS 32                    // psum slices (pass grid.y)
#define NSL_LOSS 16               // loss grid.y
#define LOG2E 1.44269504088896340736f
#define LN2 0.69314718055994530942f

typedef short short8 __attribute__((ext_vector_type(8)));
typedef float f32x4 __attribute__((ext_vector_type(4)));

__device__ __forceinline__ unsigned short f2bf(float f) {
    unsigned int u = __float_as_uint(f);
    u += 0x7FFF + ((u >> 16) & 1);
    return (unsigned short)(u >> 16);
}
__device__ __forceinline__ float bf2f(unsigned short b) {
    return __uint_as_float(((unsigned int)b) << 16);
}

// 3-term split product: z = aH*bh + aH*bl + aL*bh  (hi/lo bf16 emulated fp32)
static __device__ __forceinline__ f32x4 mfma3(const short8 aHt, const short8 aLt,
                                              const short8 bhu, const short8 blu) {
    f32x4 z = {0.f, 0.f, 0.f, 0.f};
    __builtin_amdgcn_s_setprio(1);
    z = __builtin_amdgcn_mfma_f32_16x16x32_bf16(aHt, bhu, z, 0, 0, 0);
    z = __builtin_amdgcn_mfma_f32_16x16x32_bf16(aHt, blu, z, 0, 0, 0);
    z = __builtin_amdgcn_mfma_f32_16x16x32_bf16(aLt, bhu, z, 0, 0, 0);
    __builtin_amdgcn_s_setprio(0);
    return z;
}

// ------------------------------------------------------------ prep: hi/lo split
// x side is pre-scaled by 2*log2e; y side unscaled.
__global__ void prep_split(const float* __restrict__ x, const float* __restrict__ y,
                           int nelem,
                           unsigned short* __restrict__ xh, unsigned short* __restrict__ xl,
                           unsigned short* __restrict__ yh, unsigned short* __restrict__ yl) {
    int i4 = (blockIdx.x * 256 + threadIdx.x) * 4;
    if (i4 >= 2 * nelem) return;
    const float* src; unsigned short* dh; unsigned short* dl; int off; float sc;
    if (i4 < nelem) { src = x; dh = xh; dl = xl; off = i4; sc = 2.0f * LOG2E; }
    else            { src = y; dh = yh; dl = yl; off = i4 - nelem; sc = 1.0f; }
    float4 v = *(const float4*)(src + off);
    v.x *= sc; v.y *= sc; v.z *= sc; v.w *= sc;
    ushort4 h, l;
    h.x = f2bf(v.x); l.x = f2bf(v.x - bf2f(h.x));
    h.y = f2bf(v.y); l.y = f2bf(v.y - bf2f(h.y));
    h.z = f2bf(v.z); l.z = f2bf(v.z - bf2f(h.z));
    h.w = f2bf(v.w); l.w = f2bf(v.w - bf2f(h.w));
    *(ushort4*)(dh + off) = h;
    *(ushort4*)(dl + off) = l;
}

// ------------------------------------------------------------ prep: row sumsq
// xsq/ysq raw; pb0 = exp(-ysq) multiplicative init bias (g0 = 0).
__global__ void prep_sq(const float* __restrict__ x, const float* __restrict__ y,
                        int n, float* __restrict__ xsq, float* __restrict__ ysq,
                        float* __restrict__ pb0) {
    int i = blockIdx.x * blockDim.x + threadIdx.x;
    if (i >= 2 * n) return;
    const float* src = (i < n) ? x : y;
    int r = (i < n) ? i : i - n;
    const float4* p = (const float4*)(src + (size_t)r * KDIM);
    float s = 0.f;
#pragma unroll
    for (int q = 0; q < 8; ++q) {
        float4 v = p[q];
        s += v.x * v.x + v.y * v.y + v.z * v.z + v.w * v.w;
    }
    if (i < n) xsq[r] = s;
    else { ysq[r] = s; pb0[r] = __builtin_amdgcn_exp2f(-LOG2E * s); }
}

// ------------------------------------------------------------ pass
// Wave = 32 rows; WG = 4 waves = 128 rows. grid = (n/128, NPS); slice 256 cols.
// 5 waves/SIMD (cap 102 VGPR) — round 8 retried without the spill.
__global__ __launch_bounds__(256, 5) void sink_pass(
    const unsigned short* __restrict__ Ah, const unsigned short* __restrict__ Alo,
    const unsigned short* __restrict__ Bh, const unsigned short* __restrict__ Blo,
    const float* __restrict__ pb_direct,     // pass 0: exp-bias, else null
    const float* __restrict__ psum_in,       // NPS-slice psums of prev pass
    float* __restrict__ psum_out, int n, float inv_n) {
    __shared__ float pbl[256];
    __shared__ float red[4][32][17];

    const int tid = threadIdx.x;
    const int w = tid >> 6, lane = tid & 63;
    const int mrow = lane & 15, quad = lane >> 4, koff = quad * 8;
    const int i0 = (blockIdx.x * 4 + w) * 32;
    const int jbeg = blockIdx.y * (n / NPS);

    {   // prologue: multiplicative bias for this slice's 256 cols
        int c = jbeg + tid;
        float b;
        if (pb_direct) {
            b = pb_direct[c];
        } else {
            float s = 0.f;
#pragma unroll
            for (int k = 0; k < NPS; ++k) s += psum_in[(size_t)k * n + c];
            b = inv_n / s;
        }
        pbl[tid] = b;
    }

    short8 aH[2], aL[2];
#pragma unroll
    for (int t = 0; t < 2; ++t) {
        size_t rb = (size_t)(i0 + t * 16 + mrow) * KDIM + koff;
        aH[t] = *(const short8*)(Ah + rb);
        aL[t] = *(const short8*)(Alo + rb);
    }
    __syncthreads();

    float rs[8];
#pragma unroll
    for (int q = 0; q < 8; ++q) rs[q] = 0.f;

    auto ldB = [&](int jt, short8* bh, short8* bl, float* pb) {
        const int j0 = jbeg + jt * 32;
#pragma unroll
        for (int u = 0; u < 2; ++u) {
            size_t rb = (size_t)(j0 + u * 16 + mrow) * KDIM + koff;
            bh[u] = *(const short8*)(Bh + rb);
            bl[u] = *(const short8*)(Blo + rb);
            pb[u] = pbl[jt * 32 + u * 16 + mrow];
        }
    };
    auto eproc = [&](const f32x4 z, int t, float pbu) {
#pragma unroll
        for (int r = 0; r < 4; ++r)
            rs[t * 4 + r] = fmaf(__builtin_amdgcn_exp2f(z[r]), pbu, rs[t * 4 + r]);
    };
    // Software-pipelined tile schedule (stage i MFMA overlaps stage i-1 exp);
    // accumulation order per rs element identical to plain (t,u) loop.
    auto compute = [&](short8* bh, short8* bl, float* pb) {
        f32x4 za, zb;
        za = mfma3(aH[0], aL[0], bh[0], bl[0]);
        zb = mfma3(aH[0], aL[0], bh[1], bl[1]);
        eproc(za, 0, pb[0]);
        za = mfma3(aH[1], aL[1], bh[0], bl[0]);
        eproc(zb, 0, pb[1]);
        zb = mfma3(aH[1], aL[1], bh[1], bl[1]);
        eproc(za, 1, pb[0]);
        eproc(zb, 1, pb[1]);
    };

    const int JT = (n / NPS) / 32;   // 8
    short8 bh0[2], bl0[2], bh1[2], bl1[2];
    float pb0v[2], pb1v[2];
    ldB(0, bh0, bl0, pb0v);
    for (int jt = 0; jt < JT; jt += 2) {
        ldB(jt + 1, bh1, bl1, pb1v);
        compute(bh0, bl0, pb0v);
        if (jt + 2 < JT) ldB(jt + 2, bh0, bl0, pb0v);
        compute(bh1, bl1, pb1v);
    }

#pragma unroll
    for (int t = 0; t < 2; ++t)
#pragma unroll
        for (int r = 0; r < 4; ++r)
            red[w][t * 16 + quad * 4 + r][mrow] = rs[t * 4 + r];
    __syncthreads();
    if (tid < 128) {
        int w2 = tid >> 5, row = tid & 31;
        float s = 0.f;
#pragma unroll
        for (int c = 0; c < 16; ++c) s += red[w2][row][c];
        psum_out[(size_t)blockIdx.y * n + blockIdx.x * 128 + tid] = s;
    }
}

// ------------------------------------------------------------ loss
// Wave = 32 rows; WG = 128 rows. grid = (n/128, NSL_LOSS), slice 512 cols.
// (unchanged from round 6 — protects exact final-sum order)
__global__ __launch_bounds__(256, 4) void sink_loss(
    const unsigned short* __restrict__ Xh, const unsigned short* __restrict__ Xl,
    const unsigned short* __restrict__ Yh, const unsigned short* __restrict__ Yl,
    const float* __restrict__ apsum, const float* __restrict__ bpsum,
    const float* __restrict__ xsq, const float* __restrict__ ysq,
    float* __restrict__ partials, int n, float inv_n) {
    __shared__ float pbL[512];
    __shared__ float ysl[512];
    __shared__ float pal[128];
    __shared__ float xsl[128];
    __shared__ float red[256];

    const int tid = threadIdx.x;
    const int w = tid >> 6, lane = tid & 63;
    const int mrow = lane & 15, quad = lane >> 4, koff = quad * 8;
    const int i0 = (blockIdx.x * 4 + w) * 32;
    const int jbeg = blockIdx.y * (n / NSL_LOSS);   // 512 cols

#pragma unroll
    for (int h = 0; h < 2; ++h) {
        int c = tid + h * 256;
        int j = jbeg + c;
        float s = 0.f;
#pragma unroll
        for (int k = 0; k < NPS; ++k) s += bpsum[(size_t)k * n + j];
        pbL[c] = inv_n / s;
        ysl[c] = ysq[j];
    }
    if (tid < 128) {
        int i = blockIdx.x * 128 + tid;
        float s = 0.f;
#pragma unroll
        for (int k = 0; k < NPS; ++k) s += apsum[(size_t)k * n + i];
        pal[tid] = inv_n / s;
        xsl[tid] = xsq[i];
    }

    short8 aH[2], aL[2];
#pragma unroll
    for (int t = 0; t < 2; ++t) {
        size_t rb = (size_t)(i0 + t * 16 + mrow) * KDIM + koff;
        aH[t] = *(const short8*)(Xh + rb);
        aL[t] = *(const short8*)(Xl + rb);
    }
    __syncthreads();

    float pa[8], xs[8];
#pragma unroll
    for (int t = 0; t < 2; ++t)
#pragma unroll
        for (int r = 0; r < 4; ++r) {
            int rl = w * 32 + t * 16 + quad * 4 + r;
            pa[t * 4 + r] = pal[rl];
            xs[t * 4 + r] = xsl[rl];
        }

    float acc = 0.f;

    auto ldB = [&](int jt, short8* bh, short8* bl, float* pb, float* ysv) {
#pragma unroll
        for (int u = 0; u < 2; ++u) {
            int cl = jt * 32 + u * 16 + mrow;
            size_t rb = (size_t)(jbeg + cl) * KDIM + koff;
            bh[u] = *(const short8*)(Yh + rb);
            bl[u] = *(const short8*)(Yl + rb);
            pb[u] = pbL[cl];
            ysv[u] = ysl[cl];
        }
    };
    auto eprocL = [&](const f32x4 z, int t, float pbu, float ysu) {
#pragma unroll
        for (int r = 0; r < 4; ++r) {
            float dd = z[r];
            float e = __builtin_amdgcn_exp2f(dd) * (pa[t * 4 + r] * pbu);
            float cst = fmaf(dd, -LN2, xs[t * 4 + r] + ysu);
            acc = fmaf(cst, e, acc);
        }
    };
    // Pipelined schedule preserving the original (t0,u0),(t0,u1),(t1,u0),(t1,u1)
    // accumulation order of acc.
    auto compute = [&](short8* bh, short8* bl, float* pb, float* ysv) {
        f32x4 za, zb;
        za = mfma3(aH[0], aL[0], bh[0], bl[0]);
        zb = mfma3(aH[0], aL[0], bh[1], bl[1]);
        eprocL(za, 0, pb[0], ysv[0]);
        za = mfma3(aH[1], aL[1], bh[0], bl[0]);
        eprocL(zb, 0, pb[1], ysv[1]);
        zb = mfma3(aH[1], aL[1], bh[1], bl[1]);
        eprocL(za, 1, pb[0], ysv[0]);
        eprocL(zb, 1, pb[1], ysv[1]);
    };

    const int JT = (n / NSL_LOSS) / 32;   // 16
    short8 bh0[2], bl0[2], bh1[2], bl1[2];
    float pb0v[2], pb1v[2], ys0v[2], ys1v[2];
    ldB(0, bh0, bl0, pb0v, ys0v);
    for (int jt = 0; jt < JT; jt += 2) {
        ldB(jt + 1, bh1, bl1, pb1v, ys1v);
        compute(bh0, bl0, pb0v, ys0v);
        if (jt + 2 < JT) ldB(jt + 2, bh0, bl0, pb0v, ys0v);
        compute(bh1, bl1, pb1v, ys1v);
    }

    red[tid] = acc;
    __syncthreads();
#pragma unroll
    for (int s = 128; s > 0; s >>= 1) {
        if (tid < s) red[tid] += red[tid + s];
        __syncthreads();
    }
    if (tid == 0) partials[blockIdx.y * gridDim.x + blockIdx.x] = red[0];
}

// ------------------------------------------------------------ final reduce
__global__ void sink_reduce(const float* __restrict__ p, int nb,
                            float* __restrict__ out) {
    __shared__ float red[256];
    int tid = threadIdx.x;
    float v = 0.f;
    for (int i = tid; i < nb; i += 256) v += p[i];
    red[tid] = v;
    __syncthreads();
#pragma unroll
    for (int s = 128; s > 0; s >>= 1) {
        if (tid < s) red[tid] += red[tid + s];
        __syncthreads();
    }
    if (tid == 0) out[0] = red[0];
}

// ------------------------------------------------------------ launch
extern "C" void kernel_launch(void* const* d_in, const int* in_sizes, int n_in,
                              void* d_out, int out_size, void* d_ws, size_t ws_size,
                              hipStream_t stream) {
    const float* x = (const float*)d_in[0];
    const float* y = (const float*)d_in[1];
    const int n = in_sizes[0] / KDIM;                 // 8192
    const int nelem = n * KDIM;
    const float inv_n = 1.0f / (float)n;

    float* ws = (float*)d_ws;
    float* xsq   = ws;                                //  n
    float* ysq   = ws + n;                            //  n
    float* pb0   = ws + 2 * n;                        //  n
    float* apsum = ws + 3 * n;                        //  NPS*n
    float* bpsum = ws + (3 + NPS) * n;                //  NPS*n
    float* part  = ws + (3 + 2 * NPS) * n;            //  pad n
    unsigned short* us = (unsigned short*)(ws + (4 + 2 * NPS) * n);
    unsigned short* xh = us;
    unsigned short* xl = us + nelem;
    unsigned short* yh = us + 2 * nelem;
    unsigned short* yl = us + 3 * nelem;

    dim3 pgrid(n / 128, NPS);                         // (64, 32) = 2048 WGs
    dim3 lgrid(n / 128, NSL_LOSS);                    // (64, 16) = 1024 WGs

    prep_split<<<(2 * nelem / 4 + 255) / 256, 256, 0, stream>>>(x, y, nelem, xh, xl, yh, yl);
    prep_sq<<<(2 * n + 255) / 256, 256, 0, stream>>>(x, y, n, xsq, ysq, pb0);

    sink_pass<<<pgrid, 256, 0, stream>>>(xh, xl, yh, yl, pb0, nullptr, apsum, n, inv_n);
    sink_pass<<<pgrid, 256, 0, stream>>>(yh, yl, xh, xl, nullptr, apsum, bpsum, n, inv_n);
    for (int t = 1; t < 10; ++t) {
        sink_pass<<<pgrid, 256, 0, stream>>>(xh, xl, yh, yl, nullptr, bpsum, apsum, n, inv_n);
        sink_pass<<<pgrid, 256, 0, stream>>>(yh, yl, xh, xl, nullptr, apsum, bpsum, n, inv_n);
    }
    sink_loss<<<lgrid, 256, 0, stream>>>(xh, xl, yh, yl, apsum, bpsum, xsq, ysq, part, n, inv_n);
    sink_reduce<<<1, 256, 0, stream>>>(part, (n / 128) * NSL_LOSS, (float*)d_out);
}

// Round 8
// 425.848 us; speedup vs baseline: 2.0309x; 1.1970x over previous
//
#include <hip/hip_runtime.h>
#include <math.h>

// Sinkhorn loss, n=m=8192, K=32, eps=1, L=10 iterations.
// Round 12: R6 body (best, 399us) with ONE change: B fragments single-
// buffered (drop the ping-pong prefetch pair, -16 VGPR) so
// __launch_bounds__(256,5) fits -> 5 waves/SIMD (was 4). Keeps the 64-row
// tile's arithmetic intensity (R8/R10 lesson: don't shrink tiles for waves).
// Lost prefetch = ~200cyc L1/L2 stall per ~550cyc chunk, cross-covered by
// the 5th wave. Per-cell math and accumulation order bit-identical to R6.
//   pass:  psum_out[slice*n+i] = sum_{j in slice} exp2(z_ij) * pb_j
//   loss:  sum_ij fma(z,-ln2,xsq+ysq) * exp2(z) * pa_i * pb_j
// MFMA layouts (m89/m120-verified): A elem j = A[m=lane&15][k=(lane>>4)*8+j];
// C/D: col=lane&15, row=(lane>>4)*4+reg.

#define KDIM 32
#define NPS 32                    // psum slices (pass grid.y)
#define NSL_LOSS 16               // loss grid.y
#define LOG2E 1.44269504088896340736f
#define LN2 0.69314718055994530942f

typedef short short8 __attribute__((ext_vector_type(8)));
typedef float f32x4 __attribute__((ext_vector_type(4)));

__device__ __forceinline__ unsigned short f2bf(float f) {
    unsigned int u = __float_as_uint(f);
    u += 0x7FFF + ((u >> 16) & 1);
    return (unsigned short)(u >> 16);
}
__device__ __forceinline__ float bf2f(unsigned short b) {
    return __uint_as_float(((unsigned int)b) << 16);
}

// 3-term split product: z = aH*bh + aH*bl + aL*bh  (hi/lo bf16 emulated fp32)
static __device__ __forceinline__ f32x4 mfma3(const short8 aHt, const short8 aLt,
                                              const short8 bhu, const short8 blu) {
    f32x4 z = {0.f, 0.f, 0.f, 0.f};
    __builtin_amdgcn_s_setprio(1);
    z = __builtin_amdgcn_mfma_f32_16x16x32_bf16(aHt, bhu, z, 0, 0, 0);
    z = __builtin_amdgcn_mfma_f32_16x16x32_bf16(aHt, blu, z, 0, 0, 0);
    z = __builtin_amdgcn_mfma_f32_16x16x32_bf16(aLt, bhu, z, 0, 0, 0);
    __builtin_amdgcn_s_setprio(0);
    return z;
}

// ------------------------------------------------------------ prep: hi/lo split
// x side is pre-scaled by 2*log2e; y side unscaled.
__global__ void prep_split(const float* __restrict__ x, const float* __restrict__ y,
                           int nelem,
                           unsigned short* __restrict__ xh, unsigned short* __restrict__ xl,
                           unsigned short* __restrict__ yh, unsigned short* __restrict__ yl) {
    int i4 = (blockIdx.x * 256 + threadIdx.x) * 4;
    if (i4 >= 2 * nelem) return;
    const float* src; unsigned short* dh; unsigned short* dl; int off; float sc;
    if (i4 < nelem) { src = x; dh = xh; dl = xl; off = i4; sc = 2.0f * LOG2E; }
    else            { src = y; dh = yh; dl = yl; off = i4 - nelem; sc = 1.0f; }
    float4 v = *(const float4*)(src + off);
    v.x *= sc; v.y *= sc; v.z *= sc; v.w *= sc;
    ushort4 h, l;
    h.x = f2bf(v.x); l.x = f2bf(v.x - bf2f(h.x));
    h.y = f2bf(v.y); l.y = f2bf(v.y - bf2f(h.y));
    h.z = f2bf(v.z); l.z = f2bf(v.z - bf2f(h.z));
    h.w = f2bf(v.w); l.w = f2bf(v.w - bf2f(h.w));
    *(ushort4*)(dh + off) = h;
    *(ushort4*)(dl + off) = l;
}

// ------------------------------------------------------------ prep: row sumsq
// xsq/ysq raw; pb0 = exp(-ysq) multiplicative init bias (g0 = 0).
__global__ void prep_sq(const float* __restrict__ x, const float* __restrict__ y,
                        int n, float* __restrict__ xsq, float* __restrict__ ysq,
                        float* __restrict__ pb0) {
    int i = blockIdx.x * blockDim.x + threadIdx.x;
    if (i >= 2 * n) return;
    const float* src = (i < n) ? x : y;
    int r = (i < n) ? i : i - n;
    const float4* p = (const float4*)(src + (size_t)r * KDIM);
    float s = 0.f;
#pragma unroll
    for (int q = 0; q < 8; ++q) {
        float4 v = p[q];
        s += v.x * v.x + v.y * v.y + v.z * v.z + v.w * v.w;
    }
    if (i < n) xsq[r] = s;
    else { ysq[r] = s; pb0[r] = __builtin_amdgcn_exp2f(-LOG2E * s); }
}

// ------------------------------------------------------------ pass
// Wave = 64 rows; WG = 4 waves = 256 rows. grid = (n/256, NPS); slice 256 cols.
// Single-buffered B -> ~90 live VGPR -> 5 waves/SIMD.
__global__ __launch_bounds__(256, 5) void sink_pass(
    const unsigned short* __restrict__ Ah, const unsigned short* __restrict__ Alo,
    const unsigned short* __restrict__ Bh, const unsigned short* __restrict__ Blo,
    const float* __restrict__ pb_direct,     // pass 0: exp-bias, else null
    const float* __restrict__ psum_in,       // NPS-slice psums of prev pass
    float* __restrict__ psum_out, int n, float inv_n) {
    __shared__ float pbl[256];
    __shared__ float red[4][64][17];

    const int tid = threadIdx.x;
    const int w = tid >> 6, lane = tid & 63;
    const int mrow = lane & 15, quad = lane >> 4, koff = quad * 8;
    const int i0 = (blockIdx.x * 4 + w) * 64;
    const int jbeg = blockIdx.y * (n / NPS);

    {   // prologue: multiplicative bias for this slice's 256 cols
        int c = jbeg + tid;
        float b;
        if (pb_direct) {
            b = pb_direct[c];
        } else {
            float s = 0.f;
#pragma unroll
            for (int k = 0; k < NPS; ++k) s += psum_in[(size_t)k * n + c];
            b = inv_n / s;
        }
        pbl[tid] = b;
    }

    short8 aH[4], aL[4];
#pragma unroll
    for (int t = 0; t < 4; ++t) {
        size_t rb = (size_t)(i0 + t * 16 + mrow) * KDIM + koff;
        aH[t] = *(const short8*)(Ah + rb);
        aL[t] = *(const short8*)(Alo + rb);
    }
    __syncthreads();

    float rs[16];
#pragma unroll
    for (int q = 0; q < 16; ++q) rs[q] = 0.f;

    auto ldB = [&](int jt, short8* bh, short8* bl, float* pb) {
        const int j0 = jbeg + jt * 32;
#pragma unroll
        for (int u = 0; u < 2; ++u) {
            size_t rb = (size_t)(j0 + u * 16 + mrow) * KDIM + koff;
            bh[u] = *(const short8*)(Bh + rb);
            bl[u] = *(const short8*)(Blo + rb);
            pb[u] = pbl[jt * 32 + u * 16 + mrow];
        }
    };
    auto eproc = [&](const f32x4 z, int t, float pbu) {
#pragma unroll
        for (int r = 0; r < 4; ++r)
            rs[t * 4 + r] = fmaf(__builtin_amdgcn_exp2f(z[r]), pbu, rs[t * 4 + r]);
    };
    // Software-pipelined tile schedule (stage i MFMA overlaps stage i-1 exp);
    // accumulation order per rs element identical to plain (t,u) loop.
    auto compute = [&](short8* bh, short8* bl, float* pb) {
        f32x4 za, zb;
        za = mfma3(aH[0], aL[0], bh[0], bl[0]);
        zb = mfma3(aH[0], aL[0], bh[1], bl[1]);
        eproc(za, 0, pb[0]);
        za = mfma3(aH[1], aL[1], bh[0], bl[0]);
        eproc(zb, 0, pb[1]);
        zb = mfma3(aH[1], aL[1], bh[1], bl[1]);
        eproc(za, 1, pb[0]);
        za = mfma3(aH[2], aL[2], bh[0], bl[0]);
        eproc(zb, 1, pb[1]);
        zb = mfma3(aH[2], aL[2], bh[1], bl[1]);
        eproc(za, 2, pb[0]);
        za = mfma3(aH[3], aL[3], bh[0], bl[0]);
        eproc(zb, 2, pb[1]);
        zb = mfma3(aH[3], aL[3], bh[1], bl[1]);
        eproc(za, 3, pb[0]);
        eproc(zb, 3, pb[1]);
    };

    const int JT = (n / NPS) / 32;   // 8
    short8 bh[2], bl[2];
    float pbv[2];
    for (int jt = 0; jt < JT; ++jt) {
        ldB(jt, bh, bl, pbv);
        compute(bh, bl, pbv);
    }

#pragma unroll
    for (int t = 0; t < 4; ++t)
#pragma unroll
        for (int r = 0; r < 4; ++r)
            red[w][t * 16 + quad * 4 + r][mrow] = rs[t * 4 + r];
    __syncthreads();
    {
        int w2 = tid >> 6, row = tid & 63;
        float s = 0.f;
#pragma unroll
        for (int c = 0; c < 16; ++c) s += red[w2][row][c];
        psum_out[(size_t)blockIdx.y * n + (blockIdx.x * 4 + w2) * 64 + row] = s;
    }
}

// ------------------------------------------------------------ loss
// Wave = 32 rows; WG = 128 rows. grid = (n/128, NSL_LOSS), slice 512 cols.
// (unchanged from round 6 — protects exact final-sum order)
__global__ __launch_bounds__(256, 4) void sink_loss(
    const unsigned short* __restrict__ Xh, const unsigned short* __restrict__ Xl,
    const unsigned short* __restrict__ Yh, const unsigned short* __restrict__ Yl,
    const float* __restrict__ apsum, const float* __restrict__ bpsum,
    const float* __restrict__ xsq, const float* __restrict__ ysq,
    float* __restrict__ partials, int n, float inv_n) {
    __shared__ float pbL[512];
    __shared__ float ysl[512];
    __shared__ float pal[128];
    __shared__ float xsl[128];
    __shared__ float red[256];

    const int tid = threadIdx.x;
    const int w = tid >> 6, lane = tid & 63;
    const int mrow = lane & 15, quad = lane >> 4, koff = quad * 8;
    const int i0 = (blockIdx.x * 4 + w) * 32;
    const int jbeg = blockIdx.y * (n / NSL_LOSS);   // 512 cols

#pragma unroll
    for (int h = 0; h < 2; ++h) {
        int c = tid + h * 256;
        int j = jbeg + c;
        float s = 0.f;
#pragma unroll
        for (int k = 0; k < NPS; ++k) s += bpsum[(size_t)k * n + j];
        pbL[c] = inv_n / s;
        ysl[c] = ysq[j];
    }
    if (tid < 128) {
        int i = blockIdx.x * 128 + tid;
        float s = 0.f;
#pragma unroll
        for (int k = 0; k < NPS; ++k) s += apsum[(size_t)k * n + i];
        pal[tid] = inv_n / s;
        xsl[tid] = xsq[i];
    }

    short8 aH[2], aL[2];
#pragma unroll
    for (int t = 0; t < 2; ++t) {
        size_t rb = (size_t)(i0 + t * 16 + mrow) * KDIM + koff;
        aH[t] = *(const short8*)(Xh + rb);
        aL[t] = *(const short8*)(Xl + rb);
    }
    __syncthreads();

    float pa[8], xs[8];
#pragma unroll
    for (int t = 0; t < 2; ++t)
#pragma unroll
        for (int r = 0; r < 4; ++r) {
            int rl = w * 32 + t * 16 + quad * 4 + r;
            pa[t * 4 + r] = pal[rl];
            xs[t * 4 + r] = xsl[rl];
        }

    float acc = 0.f;

    auto ldB = [&](int jt, short8* bh, short8* bl, float* pb, float* ysv) {
#pragma unroll
        for (int u = 0; u < 2; ++u) {
            int cl = jt * 32 + u * 16 + mrow;
            size_t rb = (size_t)(jbeg + cl) * KDIM + koff;
            bh[u] = *(const short8*)(Yh + rb);
            bl[u] = *(const short8*)(Yl + rb);
            pb[u] = pbL[cl];
            ysv[u] = ysl[cl];
        }
    };
    auto eprocL = [&](const f32x4 z, int t, float pbu, float ysu) {
#pragma unroll
        for (int r = 0; r < 4; ++r) {
            float dd = z[r];
            float e = __builtin_amdgcn_exp2f(dd) * (pa[t * 4 + r] * pbu);
            float cst = fmaf(dd, -LN2, xs[t * 4 + r] + ysu);
            acc = fmaf(cst, e, acc);
        }
    };
    // Pipelined schedule preserving the original (t0,u0),(t0,u1),(t1,u0),(t1,u1)
    // accumulation order of acc.
    auto compute = [&](short8* bh, short8* bl, float* pb, float* ysv) {
        f32x4 za, zb;
        za = mfma3(aH[0], aL[0], bh[0], bl[0]);
        zb = mfma3(aH[0], aL[0], bh[1], bl[1]);
        eprocL(za, 0, pb[0], ysv[0]);
        za = mfma3(aH[1], aL[1], bh[0], bl[0]);
        eprocL(zb, 0, pb[1], ysv[1]);
        zb = mfma3(aH[1], aL[1], bh[1], bl[1]);
        eprocL(za, 1, pb[0], ysv[0]);
        eprocL(zb, 1, pb[1], ysv[1]);
    };

    const int JT = (n / NSL_LOSS) / 32;   // 16
    short8 bh0[2], bl0[2], bh1[2], bl1[2];
    float pb0v[2], pb1v[2], ys0v[2], ys1v[2];
    ldB(0, bh0, bl0, pb0v, ys0v);
    for (int jt = 0; jt < JT; jt += 2) {
        ldB(jt + 1, bh1, bl1, pb1v, ys1v);
        compute(bh0, bl0, pb0v, ys0v);
        if (jt + 2 < JT) ldB(jt + 2, bh0, bl0, pb0v, ys0v);
        compute(bh1, bl1, pb1v, ys1v);
    }

    red[tid] = acc;
    __syncthreads();
#pragma unroll
    for (int s = 128; s > 0; s >>= 1) {
        if (tid < s) red[tid] += red[tid + s];
        __syncthreads();
    }
    if (tid == 0) partials[blockIdx.y * gridDim.x + blockIdx.x] = red[0];
}

// ------------------------------------------------------------ final reduce
__global__ void sink_reduce(const float* __restrict__ p, int nb,
                            float* __restrict__ out) {
    __shared__ float red[256];
    int tid = threadIdx.x;
    float v = 0.f;
    for (int i = tid; i < nb; i += 256) v += p[i];
    red[tid] = v;
    __syncthreads();
#pragma unroll
    for (int s = 128; s > 0; s >>= 1) {
        if (tid < s) red[tid] += red[tid + s];
        __syncthreads();
    }
    if (tid == 0) out[0] = red[0];
}

// ------------------------------------------------------------ launch
extern "C" void kernel_launch(void* const* d_in, const int* in_sizes, int n_in,
                              void* d_out, int out_size, void* d_ws, size_t ws_size,
                              hipStream_t stream) {
    const float* x = (const float*)d_in[0];
    const float* y = (const float*)d_in[1];
    const int n = in_sizes[0] / KDIM;                 // 8192
    const int nelem = n * KDIM;
    const float inv_n = 1.0f / (float)n;

    float* ws = (float*)d_ws;
    float* xsq   = ws;                                //  n
    float* ysq   = ws + n;                            //  n
    float* pb0   = ws + 2 * n;                        //  n
    float* apsum = ws + 3 * n;                        //  NPS*n
    float* bpsum = ws + (3 + NPS) * n;                //  NPS*n
    float* part  = ws + (3 + 2 * NPS) * n;            //  pad n
    unsigned short* us = (unsigned short*)(ws + (4 + 2 * NPS) * n);
    unsigned short* xh = us;
    unsigned short* xl = us + nelem;
    unsigned short* yh = us + 2 * nelem;
    unsigned short* yl = us + 3 * nelem;

    dim3 pgrid(n / 256, NPS);                         // (32, 32) = 1024 WGs
    dim3 lgrid(n / 128, NSL_LOSS);                    // (64, 16) = 1024 WGs

    prep_split<<<(2 * nelem / 4 + 255) / 256, 256, 0, stream>>>(x, y, nelem, xh, xl, yh, yl);
    prep_sq<<<(2 * n + 255) / 256, 256, 0, stream>>>(x, y, n, xsq, ysq, pb0);

    sink_pass<<<pgrid, 256, 0, stream>>>(xh, xl, yh, yl, pb0, nullptr, apsum, n, inv_n);
    sink_pass<<<pgrid, 256, 0, stream>>>(yh, yl, xh, xl, nullptr, apsum, bpsum, n, inv_n);
    for (int t = 1; t < 10; ++t) {
        sink_pass<<<pgrid, 256, 0, stream>>>(xh, xl, yh, yl, nullptr, bpsum, apsum, n, inv_n);
        sink_pass<<<pgrid, 256, 0, stream>>>(yh, yl, xh, xl, nullptr, apsum, bpsum, n, inv_n);
    }
    sink_loss<<<lgrid, 256, 0, stream>>>(xh, xl, yh, yl, apsum, bpsum, xsq, ysq, part, n, inv_n);
    sink_reduce<<<1, 256, 0, stream>>>(part, (n / 128) * NSL_LOSS, (float*)d_out);
}

// Round 10
// 419.165 us; speedup vs baseline: 2.0633x; 1.0159x over previous
//
#include <hip/hip_runtime.h>
#include <math.h>

// Sinkhorn loss, n=m=8192, K=32, eps=1, L=10 iterations.
// Round 14 (= R13 with the macro/brace compile error fixed via inline fn):
// R6 base (best, 399us), single change: MFMA chains issued LEVEL-INTERLEAVED
// across 4 independent tiles (4x lvl1, 4x lvl2, 4x lvl3, then 4 eprocs) so
// the ~30cyc dependent-MFMA latency inside each 3-chain is covered by the
// other 3 chains' issues. eproc order and per-rs-element accumulation order
// exactly R6's -> bit-identical numerics.
//   pass:  psum_out[slice*n+i] = sum_{j in slice} exp2(z_ij) * pb_j
//   loss:  sum_ij fma(z,-ln2,xsq+ysq) * exp2(z) * pa_i * pb_j
// MFMA layouts (m89/m120-verified): A elem j = A[m=lane&15][k=(lane>>4)*8+j];
// C/D: col=lane&15, row=(lane>>4)*4+reg.

#define KDIM 32
#define NPS 32                    // psum slices (pass grid.y)
#define NSL_LOSS 16               // loss grid.y
#define LOG2E 1.44269504088896340736f
#define LN2 0.69314718055994530942f

typedef short short8 __attribute__((ext_vector_type(8)));
typedef float f32x4 __attribute__((ext_vector_type(4)));

__device__ __forceinline__ unsigned short f2bf(float f) {
    unsigned int u = __float_as_uint(f);
    u += 0x7FFF + ((u >> 16) & 1);
    return (unsigned short)(u >> 16);
}
__device__ __forceinline__ float bf2f(unsigned short b) {
    return __uint_as_float(((unsigned int)b) << 16);
}

static __device__ __forceinline__ f32x4 mfma16(const short8 a, const short8 b,
                                               const f32x4 c) {
    return __builtin_amdgcn_mfma_f32_16x16x32_bf16(a, b, c, 0, 0, 0);
}

// ------------------------------------------------------------ prep: hi/lo split
// x side is pre-scaled by 2*log2e; y side unscaled.
__global__ void prep_split(const float* __restrict__ x, const float* __restrict__ y,
                           int nelem,
                           unsigned short* __restrict__ xh, unsigned short* __restrict__ xl,
                           unsigned short* __restrict__ yh, unsigned short* __restrict__ yl) {
    int i4 = (blockIdx.x * 256 + threadIdx.x) * 4;
    if (i4 >= 2 * nelem) return;
    const float* src; unsigned short* dh; unsigned short* dl; int off; float sc;
    if (i4 < nelem) { src = x; dh = xh; dl = xl; off = i4; sc = 2.0f * LOG2E; }
    else            { src = y; dh = yh; dl = yl; off = i4 - nelem; sc = 1.0f; }
    float4 v = *(const float4*)(src + off);
    v.x *= sc; v.y *= sc; v.z *= sc; v.w *= sc;
    ushort4 h, l;
    h.x = f2bf(v.x); l.x = f2bf(v.x - bf2f(h.x));
    h.y = f2bf(v.y); l.y = f2bf(v.y - bf2f(h.y));
    h.z = f2bf(v.z); l.z = f2bf(v.z - bf2f(h.z));
    h.w = f2bf(v.w); l.w = f2bf(v.w - bf2f(h.w));
    *(ushort4*)(dh + off) = h;
    *(ushort4*)(dl + off) = l;
}

// ------------------------------------------------------------ prep: row sumsq
// xsq/ysq raw; pb0 = exp(-ysq) multiplicative init bias (g0 = 0).
__global__ void prep_sq(const float* __restrict__ x, const float* __restrict__ y,
                        int n, float* __restrict__ xsq, float* __restrict__ ysq,
                        float* __restrict__ pb0) {
    int i = blockIdx.x * blockDim.x + threadIdx.x;
    if (i >= 2 * n) return;
    const float* src = (i < n) ? x : y;
    int r = (i < n) ? i : i - n;
    const float4* p = (const float4*)(src + (size_t)r * KDIM);
    float s = 0.f;
#pragma unroll
    for (int q = 0; q < 8; ++q) {
        float4 v = p[q];
        s += v.x * v.x + v.y * v.y + v.z * v.z + v.w * v.w;
    }
    if (i < n) xsq[r] = s;
    else { ysq[r] = s; pb0[r] = __builtin_amdgcn_exp2f(-LOG2E * s); }
}

// ------------------------------------------------------------ pass
// Wave = 64 rows; WG = 4 waves = 256 rows. grid = (n/256, NPS); slice 256 cols.
__global__ __launch_bounds__(256, 4) void sink_pass(
    const unsigned short* __restrict__ Ah, const unsigned short* __restrict__ Alo,
    const unsigned short* __restrict__ Bh, const unsigned short* __restrict__ Blo,
    const float* __restrict__ pb_direct,     // pass 0: exp-bias, else null
    const float* __restrict__ psum_in,       // NPS-slice psums of prev pass
    float* __restrict__ psum_out, int n, float inv_n) {
    __shared__ float pbl[256];
    __shared__ float red[4][64][17];

    const int tid = threadIdx.x;
    const int w = tid >> 6, lane = tid & 63;
    const int mrow = lane & 15, quad = lane >> 4, koff = quad * 8;
    const int i0 = (blockIdx.x * 4 + w) * 64;
    const int jbeg = blockIdx.y * (n / NPS);

    {   // prologue: multiplicative bias for this slice's 256 cols
        int c = jbeg + tid;
        float b;
        if (pb_direct) {
            b = pb_direct[c];
        } else {
            float s = 0.f;
#pragma unroll
            for (int k = 0; k < NPS; ++k) s += psum_in[(size_t)k * n + c];
            b = inv_n / s;
        }
        pbl[tid] = b;
    }

    short8 aH[4], aL[4];
#pragma unroll
    for (int t = 0; t < 4; ++t) {
        size_t rb = (size_t)(i0 + t * 16 + mrow) * KDIM + koff;
        aH[t] = *(const short8*)(Ah + rb);
        aL[t] = *(const short8*)(Alo + rb);
    }
    __syncthreads();

    float rs[16];
#pragma unroll
    for (int q = 0; q < 16; ++q) rs[q] = 0.f;

    auto ldB = [&](int jt, short8* bh, short8* bl, float* pb) {
        const int j0 = jbeg + jt * 32;
#pragma unroll
        for (int u = 0; u < 2; ++u) {
            size_t rb = (size_t)(j0 + u * 16 + mrow) * KDIM + koff;
            bh[u] = *(const short8*)(Bh + rb);
            bl[u] = *(const short8*)(Blo + rb);
            pb[u] = pbl[jt * 32 + u * 16 + mrow];
        }
    };
    auto eproc = [&](const f32x4 z, int t, float pbu) {
#pragma unroll
        for (int r = 0; r < 4; ++r)
            rs[t * 4 + r] = fmaf(__builtin_amdgcn_exp2f(z[r]), pbu, rs[t * 4 + r]);
    };
    // Level-interleaved MFMA issue across 4 independent tiles per batch:
    // batch tiles = (tA,u0),(tA,u1),(tB,u0),(tB,u1). Dependent-MFMA gap is
    // >=4 issue slots, covering matrix-pipe latency. eproc order identical
    // to R6: (t,u) ascending, u inner.
    auto batch4 = [&](int tA, int tB, short8* bh, short8* bl, float* pb) {
        const f32x4 zz = {0.f, 0.f, 0.f, 0.f};
        f32x4 z0, z1, z2, z3;
        __builtin_amdgcn_s_setprio(1);
        z0 = mfma16(aH[tA], bh[0], zz);
        z1 = mfma16(aH[tA], bh[1], zz);
        z2 = mfma16(aH[tB], bh[0], zz);
        z3 = mfma16(aH[tB], bh[1], zz);
        z0 = mfma16(aH[tA], bl[0], z0);
        z1 = mfma16(aH[tA], bl[1], z1);
        z2 = mfma16(aH[tB], bl[0], z2);
        z3 = mfma16(aH[tB], bl[1], z3);
        z0 = mfma16(aL[tA], bh[0], z0);
        z1 = mfma16(aL[tA], bh[1], z1);
        z2 = mfma16(aL[tB], bh[0], z2);
        z3 = mfma16(aL[tB], bh[1], z3);
        __builtin_amdgcn_s_setprio(0);
        eproc(z0, tA, pb[0]);
        eproc(z1, tA, pb[1]);
        eproc(z2, tB, pb[0]);
        eproc(z3, tB, pb[1]);
    };
    auto compute = [&](short8* bh, short8* bl, float* pb) {
        batch4(0, 1, bh, bl, pb);
        batch4(2, 3, bh, bl, pb);
    };

    const int JT = (n / NPS) / 32;   // 8
    short8 bh0[2], bl0[2], bh1[2], bl1[2];
    float pb0v[2], pb1v[2];
    ldB(0, bh0, bl0, pb0v);
    for (int jt = 0; jt < JT; jt += 2) {
        ldB(jt + 1, bh1, bl1, pb1v);
        compute(bh0, bl0, pb0v);
        if (jt + 2 < JT) ldB(jt + 2, bh0, bl0, pb0v);
        compute(bh1, bl1, pb1v);
    }

#pragma unroll
    for (int t = 0; t < 4; ++t)
#pragma unroll
        for (int r = 0; r < 4; ++r)
            red[w][t * 16 + quad * 4 + r][mrow] = rs[t * 4 + r];
    __syncthreads();
    {
        int w2 = tid >> 6, row = tid & 63;
        float s = 0.f;
#pragma unroll
        for (int c = 0; c < 16; ++c) s += red[w2][row][c];
        psum_out[(size_t)blockIdx.y * n + (blockIdx.x * 4 + w2) * 64 + row] = s;
    }
}

// ------------------------------------------------------------ loss
// Wave = 32 rows; WG = 128 rows. grid = (n/128, NSL_LOSS), slice 512 cols.
__global__ __launch_bounds__(256, 4) void sink_loss(
    const unsigned short* __restrict__ Xh, const unsigned short* __restrict__ Xl,
    const unsigned short* __restrict__ Yh, const unsigned short* __restrict__ Yl,
    const float* __restrict__ apsum, const float* __restrict__ bpsum,
    const float* __restrict__ xsq, const float* __restrict__ ysq,
    float* __restrict__ partials, int n, float inv_n) {
    __shared__ float pbL[512];
    __shared__ float ysl[512];
    __shared__ float pal[128];
    __shared__ float xsl[128];
    __shared__ float red[256];

    const int tid = threadIdx.x;
    const int w = tid >> 6, lane = tid & 63;
    const int mrow = lane & 15, quad = lane >> 4, koff = quad * 8;
    const int i0 = (blockIdx.x * 4 + w) * 32;
    const int jbeg = blockIdx.y * (n / NSL_LOSS);   // 512 cols

#pragma unroll
    for (int h = 0; h < 2; ++h) {
        int c = tid + h * 256;
        int j = jbeg + c;
        float s = 0.f;
#pragma unroll
        for (int k = 0; k < NPS; ++k) s += bpsum[(size_t)k * n + j];
        pbL[c] = inv_n / s;
        ysl[c] = ysq[j];
    }
    if (tid < 128) {
        int i = blockIdx.x * 128 + tid;
        float s = 0.f;
#pragma unroll
        for (int k = 0; k < NPS; ++k) s += apsum[(size_t)k * n + i];
        pal[tid] = inv_n / s;
        xsl[tid] = xsq[i];
    }

    short8 aH[2], aL[2];
#pragma unroll
    for (int t = 0; t < 2; ++t) {
        size_t rb = (size_t)(i0 + t * 16 + mrow) * KDIM + koff;
        aH[t] = *(const short8*)(Xh + rb);
        aL[t] = *(const short8*)(Xl + rb);
    }
    __syncthreads();

    float pa[8], xs[8];
#pragma unroll
    for (int t = 0; t < 2; ++t)
#pragma unroll
        for (int r = 0; r < 4; ++r) {
            int rl = w * 32 + t * 16 + quad * 4 + r;
            pa[t * 4 + r] = pal[rl];
            xs[t * 4 + r] = xsl[rl];
        }

    float acc = 0.f;

    auto ldB = [&](int jt, short8* bh, short8* bl, float* pb, float* ysv) {
#pragma unroll
        for (int u = 0; u < 2; ++u) {
            int cl = jt * 32 + u * 16 + mrow;
            size_t rb = (size_t)(jbeg + cl) * KDIM + koff;
            bh[u] = *(const short8*)(Yh + rb);
            bl[u] = *(const short8*)(Yl + rb);
            pb[u] = pbL[cl];
            ysv[u] = ysl[cl];
        }
    };
    auto eprocL = [&](const f32x4 z, int t, float pbu, float ysu) {
#pragma unroll
        for (int r = 0; r < 4; ++r) {
            float dd = z[r];
            float e = __builtin_amdgcn_exp2f(dd) * (pa[t * 4 + r] * pbu);
            float cst = fmaf(dd, -LN2, xs[t * 4 + r] + ysu);
            acc = fmaf(cst, e, acc);
        }
    };
    // Level-interleaved batch of the chunk's 4 tiles; acc order preserved:
    // (t0,u0),(t0,u1),(t1,u0),(t1,u1).
    auto compute = [&](short8* bh, short8* bl, float* pb, float* ysv) {
        const f32x4 zz = {0.f, 0.f, 0.f, 0.f};
        f32x4 z0, z1, z2, z3;
        __builtin_amdgcn_s_setprio(1);
        z0 = mfma16(aH[0], bh[0], zz);
        z1 = mfma16(aH[0], bh[1], zz);
        z2 = mfma16(aH[1], bh[0], zz);
        z3 = mfma16(aH[1], bh[1], zz);
        z0 = mfma16(aH[0], bl[0], z0);
        z1 = mfma16(aH[0], bl[1], z1);
        z2 = mfma16(aH[1], bl[0], z2);
        z3 = mfma16(aH[1], bl[1], z3);
        z0 = mfma16(aL[0], bh[0], z0);
        z1 = mfma16(aL[0], bh[1], z1);
        z2 = mfma16(aL[1], bh[0], z2);
        z3 = mfma16(aL[1], bh[1], z3);
        __builtin_amdgcn_s_setprio(0);
        eprocL(z0, 0, pb[0], ysv[0]);
        eprocL(z1, 0, pb[1], ysv[1]);
        eprocL(z2, 1, pb[0], ysv[0]);
        eprocL(z3, 1, pb[1], ysv[1]);
    };

    const int JT = (n / NSL_LOSS) / 32;   // 16
    short8 bh0[2], bl0[2], bh1[2], bl1[2];
    float pb0v[2], pb1v[2], ys0v[2], ys1v[2];
    ldB(0, bh0, bl0, pb0v, ys0v);
    for (int jt = 0; jt < JT; jt += 2) {
        ldB(jt + 1, bh1, bl1, pb1v, ys1v);
        compute(bh0, bl0, pb0v, ys0v);
        if (jt + 2 < JT) ldB(jt + 2, bh0, bl0, pb0v, ys0v);
        compute(bh1, bl1, pb1v, ys1v);
    }

    red[tid] = acc;
    __syncthreads();
#pragma unroll
    for (int s = 128; s > 0; s >>= 1) {
        if (tid < s) red[tid] += red[tid + s];
        __syncthreads();
    }
    if (tid == 0) partials[blockIdx.y * gridDim.x + blockIdx.x] = red[0];
}

// ------------------------------------------------------------ final reduce
__global__ void sink_reduce(const float* __restrict__ p, int nb,
                            float* __restrict__ out) {
    __shared__ float red[256];
    int tid = threadIdx.x;
    float v = 0.f;
    for (int i = tid; i < nb; i += 256) v += p[i];
    red[tid] = v;
    __syncthreads();
#pragma unroll
    for (int s = 128; s > 0; s >>= 1) {
        if (tid < s) red[tid] += red[tid + s];
        __syncthreads();
    }
    if (tid == 0) out[0] = red[0];
}

// ------------------------------------------------------------ launch
extern "C" void kernel_launch(void* const* d_in, const int* in_sizes, int n_in,
                              void* d_out, int out_size, void* d_ws, size_t ws_size,
                              hipStream_t stream) {
    const float* x = (const float*)d_in[0];
    const float* y = (const float*)d_in[1];
    const int n = in_sizes[0] / KDIM;                 // 8192
    const int nelem = n * KDIM;
    const float inv_n = 1.0f / (float)n;

    float* ws = (float*)d_ws;
    float* xsq   = ws;                                //  n
    float* ysq   = ws + n;                            //  n
    float* pb0   = ws + 2 * n;                        //  n
    float* apsum = ws + 3 * n;                        //  NPS*n
    float* bpsum = ws + (3 + NPS) * n;                //  NPS*n
    float* part  = ws + (3 + 2 * NPS) * n;            //  pad n
    unsigned short* us = (unsigned short*)(ws + (4 + 2 * NPS) * n);
    unsigned short* xh = us;
    unsigned short* xl = us + nelem;
    unsigned short* yh = us + 2 * nelem;
    unsigned short* yl = us + 3 * nelem;

    dim3 pgrid(n / 256, NPS);                         // (32, 32) = 1024 WGs
    dim3 lgrid(n / 128, NSL_LOSS);                    // (64, 16) = 1024 WGs

    prep_split<<<(2 * nelem / 4 + 255) / 256, 256, 0, stream>>>(x, y, nelem, xh, xl, yh, yl);
    prep_sq<<<(2 * n + 255) / 256, 256, 0, stream>>>(x, y, n, xsq, ysq, pb0);

    sink_pass<<<pgrid, 256, 0, stream>>>(xh, xl, yh, yl, pb0, nullptr, apsum, n, inv_n);
    sink_pass<<<pgrid, 256, 0, stream>>>(yh, yl, xh, xl, nullptr, apsum, bpsum, n, inv_n);
    for (int t = 1; t < 10; ++t) {
        sink_pass<<<pgrid, 256, 0, stream>>>(xh, xl, yh, yl, nullptr, bpsum, apsum, n, inv_n);
        sink_pass<<<pgrid, 256, 0, stream>>>(yh, yl, xh, xl, nullptr, apsum, bpsum, n, inv_n);
    }
    sink_loss<<<lgrid, 256, 0, stream>>>(xh, xl, yh, yl, apsum, bpsum, xsq, ysq, part, n, inv_n);
    sink_reduce<<<1, 256, 0, stream>>>(part, (n / 128) * NSL_LOSS, (float*)d_out);
}